// Round 3
// baseline (135.845 us; speedup 1.0000x reference)
//
#include <hip/hip_runtime.h>

#define B_BATCH 16
#define XLEN    320000
#define NFFT    2048
#define HOP     512
#define PADW    1024
#define NFREQ   1025
#define T_OUT   626
#define M_ROWS  2050
#define NCOLS   (B_BATCH * T_OUT)          // 10016
#define BM      128
#define BN      256
#define BK      64
#define MT2     17                          // ceil(2050/128)
#define NT2     40                          // ceil(10016/256)
#define KT2     32                          // 2048/64

#define XPAD_LEN    322048                  // XLEN + 2*PADW
#define XPAD_STRIDE 330240
#define APACK_BYTES ((size_t)MT2 * KT2 * 2 * 8192)             // 8,912,896
#define XPAD_BYTES  ((size_t)(B_BATCH + 1) * XPAD_STRIDE * 2)  // 11,228,160 (batch 16 = zeros)
#define WS_NEEDED   (APACK_BYTES + XPAD_BYTES)

typedef __bf16 bf16x8 __attribute__((ext_vector_type(8)));
typedef __bf16 bf16x4 __attribute__((ext_vector_type(4)));
typedef float  f32x4  __attribute__((ext_vector_type(4)));

__device__ __forceinline__ void gload_lds16(const void* g, void* l) {
    __builtin_amdgcn_global_load_lds(
        (const __attribute__((address_space(1))) unsigned int*)g,
        (__attribute__((address_space(3))) unsigned int*)l,
        16, 0, 0);
}

// ---------------- prep A: weights fp32 -> bf16, packed in exact LDS-slot layout ----
// Slot (mt,kt,ks) = 8 KB: cell (row in [0,128), scell in [0,4)) at byte row*64+scell*16
// holds W[mt*128+row][kt*64 + ks*32 + (scell^(row&3))*8 + e], e in [0,8).
__global__ __launch_bounds__(256) void prep_w(
    const float* __restrict__ wre, const float* __restrict__ wim,
    __bf16* __restrict__ apack)
{
    const int gid  = blockIdx.x * 256 + threadIdx.x;  // cell id, 17*32*2*512 = 557056
    const int scell = gid & 3;
    const int row   = (gid >> 2) & 127;
    const int ks    = (gid >> 9) & 1;
    const int kt    = (gid >> 10) & 31;
    const int mt    = gid >> 15;

    const int grow = mt * 128 + row;
    const int k    = kt * 64 + ks * 32 + ((scell ^ (row & 3)) << 3);

    bf16x8 v = bf16x8{};
    if (grow < M_ROWS) {
        const float* src = (grow < NFREQ)
            ? (wre + (size_t)grow * NFFT + k)
            : (wim + (size_t)(grow - NFREQ) * NFFT + k);
        const float4 a = *reinterpret_cast<const float4*>(src);
        const float4 b = *reinterpret_cast<const float4*>(src + 4);
        v[0] = (__bf16)a.x; v[1] = (__bf16)a.y; v[2] = (__bf16)a.z; v[3] = (__bf16)a.w;
        v[4] = (__bf16)b.x; v[5] = (__bf16)b.y; v[6] = (__bf16)b.z; v[7] = (__bf16)b.w;
    }
    *reinterpret_cast<bf16x8*>(apack + (size_t)gid * 8) = v;
}

// ---------------- prep B: reflect-padded signal fp32 -> bf16 (batch 16 = zeros) ----
__global__ __launch_bounds__(256) void prep_x(
    const float* __restrict__ x, __bf16* __restrict__ xpad)
{
    const int gid = blockIdx.x * 256 + threadIdx.x;
    if (gid >= (B_BATCH + 1) * (XPAD_STRIDE / 8)) return;
    const int b  = gid / (XPAD_STRIDE / 8);
    const int i0 = (gid - b * (XPAD_STRIDE / 8)) * 8;

    bf16x8 v = bf16x8{};
    if (b < B_BATCH) {
        const float* xb = x + (size_t)b * XLEN;
        const int pos0 = i0 - PADW;
        if (pos0 >= 0 && pos0 + 8 <= XLEN) {
            const float4 a = *reinterpret_cast<const float4*>(xb + pos0);
            const float4 c = *reinterpret_cast<const float4*>(xb + pos0 + 4);
            v[0] = (__bf16)a.x; v[1] = (__bf16)a.y; v[2] = (__bf16)a.z; v[3] = (__bf16)a.w;
            v[4] = (__bf16)c.x; v[5] = (__bf16)c.y; v[6] = (__bf16)c.z; v[7] = (__bf16)c.w;
        } else {
            #pragma unroll
            for (int e = 0; e < 8; ++e) {
                const int i = i0 + e;
                if (i >= XPAD_LEN) { v[e] = (__bf16)0.f; continue; }
                int p = i - PADW;
                p = (p < 0) ? -p : p;
                p = (p >= XLEN) ? (2 * XLEN - 2 - p) : p;
                v[e] = (__bf16)xb[p];
            }
        }
    }
    *reinterpret_cast<bf16x8*>(xpad + (size_t)b * XPAD_STRIDE + i0) = v;
}

// ---------------- main GEMM: phase-pipelined, counted vmcnt ----------------
// LDS: A slots (buf*2+kh)*8192, 32 KB total; B slots 32768 + (buf*2+kh)*16384, 64 KB.
// Tile t: phase1 reads Kh0, phase2 reads Kh1. Issues: t.ph1 -> Kh1(t+1); t.ph2 -> Kh0(t+2).
// vmcnt(3) at each tile end leaves exactly the newest phase's 3 loads in flight.

#define MFMA16 __builtin_amdgcn_mfma_f32_16x16x32_bf16

#define PH(BUF, KS, STAGE, VMW) do {                                              \
    const unsigned abase = (unsigned)(((BUF)*2+(KS)) << 13) + offA_base;          \
    const unsigned bbase = (unsigned)(((BUF)*2+(KS)) << 14) + offB_base;          \
    bf16x8 a0 = *(const bf16x8*)(lds + abase);                                    \
    bf16x8 a1 = *(const bf16x8*)(lds + abase + 1024);                             \
    bf16x8 a2 = *(const bf16x8*)(lds + abase + 2048);                             \
    bf16x8 a3 = *(const bf16x8*)(lds + abase + 3072);                             \
    bf16x8 b0 = *(const bf16x8*)(lds + bbase);                                    \
    bf16x8 b1 = *(const bf16x8*)(lds + bbase + 1024);                             \
    bf16x8 b2 = *(const bf16x8*)(lds + bbase + 2048);                             \
    bf16x8 b3 = *(const bf16x8*)(lds + bbase + 3072);                             \
    STAGE                                                                          \
    VMW                                                                            \
    __builtin_amdgcn_s_barrier();                                                  \
    __builtin_amdgcn_s_setprio(1);                                                 \
    acc[0][0] = MFMA16(a0, b0, acc[0][0], 0, 0, 0);                                \
    acc[0][1] = MFMA16(a0, b1, acc[0][1], 0, 0, 0);                                \
    acc[0][2] = MFMA16(a0, b2, acc[0][2], 0, 0, 0);                                \
    acc[0][3] = MFMA16(a0, b3, acc[0][3], 0, 0, 0);                                \
    acc[1][0] = MFMA16(a1, b0, acc[1][0], 0, 0, 0);                                \
    acc[1][1] = MFMA16(a1, b1, acc[1][1], 0, 0, 0);                                \
    acc[1][2] = MFMA16(a1, b2, acc[1][2], 0, 0, 0);                                \
    acc[1][3] = MFMA16(a1, b3, acc[1][3], 0, 0, 0);                                \
    acc[2][0] = MFMA16(a2, b0, acc[2][0], 0, 0, 0);                                \
    acc[2][1] = MFMA16(a2, b1, acc[2][1], 0, 0, 0);                                \
    acc[2][2] = MFMA16(a2, b2, acc[2][2], 0, 0, 0);                                \
    acc[2][3] = MFMA16(a2, b3, acc[2][3], 0, 0, 0);                                \
    acc[3][0] = MFMA16(a3, b0, acc[3][0], 0, 0, 0);                                \
    acc[3][1] = MFMA16(a3, b1, acc[3][1], 0, 0, 0);                                \
    acc[3][2] = MFMA16(a3, b2, acc[3][2], 0, 0, 0);                                \
    acc[3][3] = MFMA16(a3, b3, acc[3][3], 0, 0, 0);                                \
    __builtin_amdgcn_s_setprio(0);                                                 \
    __builtin_amdgcn_s_barrier();                                                  \
    __builtin_amdgcn_sched_barrier(0);                                             \
} while (0)

#define VM3 asm volatile("s_waitcnt vmcnt(3)" ::: "memory");
#define VM0 asm volatile("s_waitcnt vmcnt(0)" ::: "memory");

__global__ __launch_bounds__(512, 2) void stft_gemm3(
    const __bf16* __restrict__ apack,
    const __bf16* __restrict__ xpad,
    float* __restrict__ out)
{
    __shared__ __align__(16) unsigned char lds[98304];

    const int tid  = threadIdx.x;
    const int lane = tid & 63;
    const int wid  = tid >> 6;
    const int wm   = wid >> 2;   // 0..1
    const int wn   = wid & 3;    // 0..3
    const int fr   = lane & 15;
    const int kq   = lane >> 4;

    // bijective XCD-chunked swizzle: 680 = 8 * 85
    const int orig = (blockIdx.x & 7) * 85 + (blockIdx.x >> 3);
    const int nt = orig / MT2;
    const int mt = orig % MT2;

    // ---- staging bases
    const char* ablk = (const char*)apack + ((size_t)mt * KT2 * 2) * 8192 + (size_t)tid * 16;

    const char* xpb = (const char*)xpad;
    const int c0 = tid, c1 = tid + 512;
    const char* gb0;
    const char* gb1;
    {
        int row = c0 >> 2;
        int col = nt * 256 + row;
        unsigned b = (unsigned)col / 626u;
        int tc = col - (int)b * 626;
        int kqv = (c0 & 3) ^ (row & 3);
        gb0 = xpb + ((size_t)b * XPAD_STRIDE + (size_t)tc * 512) * 2 + kqv * 16;
        row = c1 >> 2;
        col = nt * 256 + row;
        b = (unsigned)col / 626u;
        tc = col - (int)b * 626;
        kqv = (c1 & 3) ^ (row & 3);
        gb1 = xpb + ((size_t)b * XPAD_STRIDE + (size_t)tc * 512) * 2 + kqv * 16;
    }

    auto stageA = [&](int kt, int ks, int buf) {
        gload_lds16(ablk + ((size_t)(kt * 2 + ks) << 13),
                    lds + ((buf * 2 + ks) << 13) + (wid << 10));
    };
    auto stageB = [&](int kt, int ks, int buf) {
        const int koff = kt * 128 + ks * 64;
        unsigned char* d = lds + 32768 + ((buf * 2 + ks) << 14) + (wid << 10);
        gload_lds16(gb0 + koff, d);
        gload_lds16(gb1 + koff, d + 8192);
    };

    // ---- ds_read bases (swizzled cell layout: row*64 + 16*((kq^row)&3))
    const unsigned swz = (unsigned)(((kq ^ fr) & 3) << 4);
    const unsigned offA_base = (unsigned)((wm * 64 + fr) * 64) + swz;
    const unsigned offB_base = 32768u + (unsigned)((wn * 64 + fr) * 64) + swz;

    f32x4 acc[4][4];
    #pragma unroll
    for (int m = 0; m < 4; ++m)
        #pragma unroll
        for (int n = 0; n < 4; ++n)
            acc[m][n] = f32x4{0.f, 0.f, 0.f, 0.f};

    // ---- prologue: tile0 Kh0+Kh1, tile1 Kh0; leave tile1-Kh0 (3 loads) in flight
    stageA(0, 0, 0); stageB(0, 0, 0);
    stageA(0, 1, 0); stageB(0, 1, 0);
    stageA(1, 0, 1); stageB(1, 0, 1);
    VM3
    __builtin_amdgcn_s_barrier();
    __builtin_amdgcn_sched_barrier(0);

    // ---- main loop: tiles 0..29, fully pipelined
    #pragma unroll 1
    for (int i = 0; i < 15; ++i) {
        const int t0 = 2 * i;
        PH(0, 0, stageA(t0 + 1, 1, 1); stageB(t0 + 1, 1, 1);, );
        PH(0, 1, stageA(t0 + 2, 0, 0); stageB(t0 + 2, 0, 0);, VM3);
        PH(1, 0, stageA(t0 + 2, 1, 0); stageB(t0 + 2, 1, 0);, );
        PH(1, 1, stageA(t0 + 3, 0, 1); stageB(t0 + 3, 0, 1);, VM3);
    }
    // ---- tail: t=30 (stage only Kh1(31), then drain), t=31 (no stages)
    PH(0, 0, stageA(31, 1, 1); stageB(31, 1, 1);, );
    PH(0, 1, , VM0);
    PH(1, 0, , );
    PH(1, 1, , );

    // ---- epilogue: C/D layout col = lane&15, row = kq*4 + j
    const size_t imag_base = (size_t)B_BATCH * NFREQ * T_OUT;
    #pragma unroll
    for (int n = 0; n < 4; ++n) {
        const int col = nt * 256 + wn * 64 + n * 16 + fr;
        if (col < NCOLS) {
            const unsigned b = (unsigned)col / 626u;
            const int tc = col - (int)b * 626;
            const size_t colbase = (size_t)b * NFREQ * T_OUT + (size_t)tc;
            #pragma unroll
            for (int m = 0; m < 4; ++m) {
                #pragma unroll
                for (int j = 0; j < 4; ++j) {
                    const int grow = mt * 128 + wm * 64 + m * 16 + kq * 4 + j;
                    if (grow < M_ROWS) {
                        const size_t off = (grow < NFREQ)
                            ? colbase + (size_t)grow * T_OUT
                            : imag_base + colbase + (size_t)(grow - NFREQ) * T_OUT;
                        out[off] = acc[m][n][j];
                    }
                }
            }
        }
    }
}

// ---------------- no-workspace fallback (round-1 structure) ----------------
__device__ __forceinline__ unsigned lds_off_fb(int row, int kbyte) {
    return (unsigned)(row * 128 + (kbyte ^ ((row & 7) << 4)));
}

__global__ __launch_bounds__(256) void stft_gemm_fb(
    const float* __restrict__ x,
    const float* __restrict__ wre,
    const float* __restrict__ wim,
    float* __restrict__ out)
{
    __shared__ __align__(16) unsigned char ldsA[128 * 128];
    __shared__ __align__(16) unsigned char ldsB[128 * 128];

    const int tid  = threadIdx.x;
    const int lane = tid & 63;
    const int wid  = tid >> 6;
    const int wmf  = wid >> 1;
    const int wnf  = wid & 1;

    const int bid = blockIdx.x;
    const int b   = bid / (17 * 5);
    const int rem = bid % (17 * 5);
    const int mt  = rem / 5;
    const int nt  = rem % 5;

    const int row0 = mt * 128;
    const int col0 = nt * 128;
    const float* xb = x + (size_t)b * XLEN;

    const int c4 = (tid & 15) * 4;
    const int r0 = tid >> 4;

    f32x4 acc[4][4];
    #pragma unroll
    for (int m = 0; m < 4; ++m)
        #pragma unroll
        for (int n = 0; n < 4; ++n)
            acc[m][n] = f32x4{0.f, 0.f, 0.f, 0.f};

    const int fr = lane & 15;
    const int kq = lane >> 4;

    for (int k0 = 0; k0 < NFFT; k0 += 64) {
        bf16x4 sa[8], sb[8];
        #pragma unroll
        for (int rr = 0; rr < 8; ++rr) {
            const int row  = rr * 16 + r0;
            const int grow = row0 + row;
            float4 v = make_float4(0.f, 0.f, 0.f, 0.f);
            if (grow < M_ROWS) {
                const float* wsrc = (grow < NFREQ)
                    ? (wre + (size_t)grow * NFFT)
                    : (wim + (size_t)(grow - NFREQ) * NFFT);
                v = *reinterpret_cast<const float4*>(wsrc + k0 + c4);
            }
            sa[rr].x = (__bf16)v.x; sa[rr].y = (__bf16)v.y;
            sa[rr].z = (__bf16)v.z; sa[rr].w = (__bf16)v.w;
        }
        #pragma unroll
        for (int rr = 0; rr < 8; ++rr) {
            const int trow = rr * 16 + r0;
            const int t    = col0 + trow;
            float4 v = make_float4(0.f, 0.f, 0.f, 0.f);
            if (t < T_OUT) {
                const int pos = t * HOP + k0 + c4 - PADW;
                if (pos >= 0 && pos <= XLEN - 4) {
                    v = *reinterpret_cast<const float4*>(xb + pos);
                } else {
                    float tmp[4];
                    #pragma unroll
                    for (int e = 0; e < 4; ++e) {
                        int p = pos + e;
                        p = (p < 0) ? -p : p;
                        p = (p >= XLEN) ? (2 * XLEN - 2 - p) : p;
                        tmp[e] = xb[p];
                    }
                    v = make_float4(tmp[0], tmp[1], tmp[2], tmp[3]);
                }
            }
            sb[rr].x = (__bf16)v.x; sb[rr].y = (__bf16)v.y;
            sb[rr].z = (__bf16)v.z; sb[rr].w = (__bf16)v.w;
        }
        __syncthreads();
        #pragma unroll
        for (int rr = 0; rr < 8; ++rr) {
            const int row = rr * 16 + r0;
            *reinterpret_cast<bf16x4*>(ldsA + lds_off_fb(row, c4 * 2)) = sa[rr];
            *reinterpret_cast<bf16x4*>(ldsB + lds_off_fb(row, c4 * 2)) = sb[rr];
        }
        __syncthreads();
        #pragma unroll
        for (int kk = 0; kk < 2; ++kk) {
            const int kbyte = kk * 64 + kq * 16;
            bf16x8 af[4], bfv[4];
            #pragma unroll
            for (int m = 0; m < 4; ++m)
                af[m] = *reinterpret_cast<const bf16x8*>(
                    ldsA + lds_off_fb(wmf * 64 + m * 16 + fr, kbyte));
            #pragma unroll
            for (int n = 0; n < 4; ++n)
                bfv[n] = *reinterpret_cast<const bf16x8*>(
                    ldsB + lds_off_fb(wnf * 64 + n * 16 + fr, kbyte));
            #pragma unroll
            for (int m = 0; m < 4; ++m)
                #pragma unroll
                for (int n = 0; n < 4; ++n)
                    acc[m][n] = MFMA16(af[m], bfv[n], acc[m][n], 0, 0, 0);
        }
    }

    const size_t imag_base = (size_t)B_BATCH * NFREQ * T_OUT;
    #pragma unroll
    for (int m = 0; m < 4; ++m) {
        #pragma unroll
        for (int n = 0; n < 4; ++n) {
            #pragma unroll
            for (int j = 0; j < 4; ++j) {
                const int grow = row0 + wmf * 64 + m * 16 + kq * 4 + j;
                const int gcol = col0 + wnf * 64 + n * 16 + fr;
                if (grow < M_ROWS && gcol < T_OUT) {
                    size_t off;
                    if (grow < NFREQ)
                        off = ((size_t)b * NFREQ + grow) * T_OUT + gcol;
                    else
                        off = imag_base + ((size_t)b * NFREQ + (grow - NFREQ)) * T_OUT + gcol;
                    out[off] = acc[m][n][j];
                }
            }
        }
    }
}

extern "C" void kernel_launch(void* const* d_in, const int* in_sizes, int n_in,
                              void* d_out, int out_size, void* d_ws, size_t ws_size,
                              hipStream_t stream) {
    const float* x   = (const float*)d_in[0];
    const float* wre = (const float*)d_in[1];
    const float* wim = (const float*)d_in[2];
    float* out = (float*)d_out;

    if (ws_size < WS_NEEDED) {
        stft_gemm_fb<<<dim3(B_BATCH * 17 * 5), 256, 0, stream>>>(x, wre, wim, out);
        return;
    }

    __bf16* apack = (__bf16*)d_ws;
    __bf16* xpad  = (__bf16*)((char*)d_ws + APACK_BYTES);

    prep_w<<<dim3(557056 / 256), 256, 0, stream>>>(wre, wim, apack);
    prep_x<<<dim3(((B_BATCH + 1) * (XPAD_STRIDE / 8) + 255) / 256), 256, 0, stream>>>(x, xpad);
    stft_gemm3<<<dim3(MT2 * NT2), 512, 0, stream>>>(apack, xpad, out);
}

// Round 4
// 112.931 us; speedup vs baseline: 1.2029x; 1.2029x over previous
//
#include <hip/hip_runtime.h>

#define B_BATCH 16
#define XLEN    320000
#define NFFT    2048
#define HOP     512
#define PADW    1024
#define NFREQ   1025
#define T_OUT   626
#define M_ROWS  2050
#define NCOLS   (B_BATCH * T_OUT)          // 10016
#define MT2     17                          // ceil(2050/128)
#define NT2     40                          // ceil(10016/256)
#define KT2     32                          // 2048/64

#define XPAD_LEN    322048                  // XLEN + 2*PADW
#define XPAD_STRIDE 330240
#define APACK_BYTES ((size_t)MT2 * KT2 * 2 * 8192)             // 8,912,896
#define XPAD_BYTES  ((size_t)(B_BATCH + 1) * XPAD_STRIDE * 2)  // 11,228,160 (slot 16 = zeros)
#define WS_NEEDED   (APACK_BYTES + XPAD_BYTES)

typedef __bf16 bf16x8 __attribute__((ext_vector_type(8)));
typedef __bf16 bf16x4 __attribute__((ext_vector_type(4)));
typedef float  f32x4  __attribute__((ext_vector_type(4)));

__device__ __forceinline__ void gload_lds16(const void* g, void* l) {
    __builtin_amdgcn_global_load_lds(
        (const __attribute__((address_space(1))) unsigned int*)g,
        (__attribute__((address_space(3))) unsigned int*)l,
        16, 0, 0);
}

// ---------------- prep A: weights fp32 -> bf16, packed in exact LDS-slot layout ----
// Half-slot (mt,kt,ks) = 8 KB: byte row*64 + scell*16 holds
// W[mt*128+row][kt*64 + ks*32 + ((scell ^ ((row>>1)&3))<<3) + e], e in [0,8).
// Swizzle (row>>1)&3: within any 8 consecutive rows, (row&1, swz) covers all
// 8 bank-groups -> conflict-free ds_read_b128 (round-3's (row&3) collided).
__global__ __launch_bounds__(256) void prep_w(
    const float* __restrict__ wre, const float* __restrict__ wim,
    __bf16* __restrict__ apack)
{
    const int gid   = blockIdx.x * 256 + threadIdx.x;  // 557056 total
    const int scell = gid & 3;
    const int row   = (gid >> 2) & 127;
    const int ks    = (gid >> 9) & 1;
    const int kt    = (gid >> 10) & 31;
    const int mt    = gid >> 15;

    const int grow = mt * 128 + row;
    const int k    = kt * 64 + ks * 32 + (((scell ^ (row >> 1)) & 3) << 3);

    bf16x8 v = bf16x8{};
    if (grow < M_ROWS) {
        const float* src = (grow < NFREQ)
            ? (wre + (size_t)grow * NFFT + k)
            : (wim + (size_t)(grow - NFREQ) * NFFT + k);
        const float4 a = *reinterpret_cast<const float4*>(src);
        const float4 b = *reinterpret_cast<const float4*>(src + 4);
        v[0] = (__bf16)a.x; v[1] = (__bf16)a.y; v[2] = (__bf16)a.z; v[3] = (__bf16)a.w;
        v[4] = (__bf16)b.x; v[5] = (__bf16)b.y; v[6] = (__bf16)b.z; v[7] = (__bf16)b.w;
    }
    *reinterpret_cast<bf16x8*>(apack + (size_t)gid * 8) = v;
}

// ---------------- prep B: reflect-padded signal fp32 -> bf16 (slot 16 = zeros) ----
__global__ __launch_bounds__(256) void prep_x(
    const float* __restrict__ x, __bf16* __restrict__ xpad)
{
    const int gid = blockIdx.x * 256 + threadIdx.x;
    if (gid >= (B_BATCH + 1) * (XPAD_STRIDE / 8)) return;
    const int b  = gid / (XPAD_STRIDE / 8);
    const int i0 = (gid - b * (XPAD_STRIDE / 8)) * 8;

    bf16x8 v = bf16x8{};
    if (b < B_BATCH) {
        const float* xb = x + (size_t)b * XLEN;
        const int pos0 = i0 - PADW;
        if (pos0 >= 0 && pos0 + 8 <= XLEN) {
            const float4 a = *reinterpret_cast<const float4*>(xb + pos0);
            const float4 c = *reinterpret_cast<const float4*>(xb + pos0 + 4);
            v[0] = (__bf16)a.x; v[1] = (__bf16)a.y; v[2] = (__bf16)a.z; v[3] = (__bf16)a.w;
            v[4] = (__bf16)c.x; v[5] = (__bf16)c.y; v[6] = (__bf16)c.z; v[7] = (__bf16)c.w;
        } else {
            #pragma unroll
            for (int e = 0; e < 8; ++e) {
                const int i = i0 + e;
                if (i >= XPAD_LEN) { v[e] = (__bf16)0.f; continue; }
                int p = i - PADW;
                p = (p < 0) ? -p : p;
                p = (p >= XLEN) ? (2 * XLEN - 2 - p) : p;
                v[e] = (__bf16)xb[p];
            }
        }
    }
    *reinterpret_cast<bf16x8*>(xpad + (size_t)b * XPAD_STRIDE + i0) = v;
}

// ---------------- main GEMM: 3-slot rotating pipeline, counted vmcnt ----------------
// Phase p (p = kt*2 + ks, 64 phases): reads slot p%3, issues stage(p+2) into
// slot (p+2)%3 (freed at end of phase p-1). Per-phase: vmcnt(3) -> barrier ->
// 8 ds_read_b128 -> 3 global_load_lds -> 16 MFMA. LDS = 3*(8K A + 16K B) = 72 KB
// -> 2 blocks/CU.

#define MFMA16 __builtin_amdgcn_mfma_f32_16x16x32_bf16

#define VM3 asm volatile("s_waitcnt vmcnt(3)" ::: "memory");
#define VM0 asm volatile("s_waitcnt vmcnt(0)" ::: "memory");

#define STG(KT_, KS_, SLOT_) do {                                                  \
    gload_lds16(ablk + (((KT_) * 2 + (KS_)) << 13),                                \
                lds + ((SLOT_) << 13) + (wid << 10));                              \
    {                                                                              \
        const int koff = (KT_) * 128 + (KS_) * 64;                                 \
        unsigned char* d_ = lds + 24576 + ((SLOT_) << 14) + (wid << 10);           \
        gload_lds16(gb0 + koff, d_);                                               \
        gload_lds16(gb1 + koff, d_ + 8192);                                        \
    }                                                                              \
} while (0)

#define PH3(SLOT_, STAGE_, VMW_) do {                                              \
    VMW_                                                                           \
    __builtin_amdgcn_s_barrier();                                                  \
    __builtin_amdgcn_sched_barrier(0);                                             \
    const unsigned abase = ((SLOT_) << 13) + offA_base;                            \
    const unsigned bbase = 24576u + ((SLOT_) << 14) + offB_base;                   \
    bf16x8 a0 = *(const bf16x8*)(lds + abase);                                     \
    bf16x8 a1 = *(const bf16x8*)(lds + abase + 1024);                              \
    bf16x8 a2 = *(const bf16x8*)(lds + abase + 2048);                              \
    bf16x8 a3 = *(const bf16x8*)(lds + abase + 3072);                              \
    bf16x8 b0 = *(const bf16x8*)(lds + bbase);                                     \
    bf16x8 b1 = *(const bf16x8*)(lds + bbase + 1024);                              \
    bf16x8 b2 = *(const bf16x8*)(lds + bbase + 2048);                              \
    bf16x8 b3 = *(const bf16x8*)(lds + bbase + 3072);                              \
    STAGE_                                                                         \
    __builtin_amdgcn_s_setprio(1);                                                 \
    acc[0][0] = MFMA16(a0, b0, acc[0][0], 0, 0, 0);                                \
    acc[0][1] = MFMA16(a0, b1, acc[0][1], 0, 0, 0);                                \
    acc[0][2] = MFMA16(a0, b2, acc[0][2], 0, 0, 0);                                \
    acc[0][3] = MFMA16(a0, b3, acc[0][3], 0, 0, 0);                                \
    acc[1][0] = MFMA16(a1, b0, acc[1][0], 0, 0, 0);                                \
    acc[1][1] = MFMA16(a1, b1, acc[1][1], 0, 0, 0);                                \
    acc[1][2] = MFMA16(a1, b2, acc[1][2], 0, 0, 0);                                \
    acc[1][3] = MFMA16(a1, b3, acc[1][3], 0, 0, 0);                                \
    acc[2][0] = MFMA16(a2, b0, acc[2][0], 0, 0, 0);                                \
    acc[2][1] = MFMA16(a2, b1, acc[2][1], 0, 0, 0);                                \
    acc[2][2] = MFMA16(a2, b2, acc[2][2], 0, 0, 0);                                \
    acc[2][3] = MFMA16(a2, b3, acc[2][3], 0, 0, 0);                                \
    acc[3][0] = MFMA16(a3, b0, acc[3][0], 0, 0, 0);                                \
    acc[3][1] = MFMA16(a3, b1, acc[3][1], 0, 0, 0);                                \
    acc[3][2] = MFMA16(a3, b2, acc[3][2], 0, 0, 0);                                \
    acc[3][3] = MFMA16(a3, b3, acc[3][3], 0, 0, 0);                                \
    __builtin_amdgcn_s_setprio(0);                                                 \
} while (0)

__global__ __launch_bounds__(512, 4) void stft_gemm4(
    const __bf16* __restrict__ apack,
    const __bf16* __restrict__ xpad,
    float* __restrict__ out)
{
    __shared__ __align__(16) unsigned char lds[73728];   // 72 KB -> 2 blocks/CU

    const int tid  = threadIdx.x;
    const int lane = tid & 63;
    const int wid  = tid >> 6;
    const int wm   = wid >> 2;   // 0..1
    const int wn   = wid & 3;    // 0..3
    const int fr   = lane & 15;
    const int kq   = lane >> 4;

    // bijective XCD-chunked swizzle: 680 = 8 * 85
    const int orig = (blockIdx.x & 7) * 85 + (blockIdx.x >> 3);
    const int nt = orig / MT2;
    const int mt = orig % MT2;

    // ---- staging bases
    const char* ablk = (const char*)apack + (size_t)mt * (KT2 * 2 * 8192) + (size_t)tid * 16;

    const char* xpb = (const char*)xpad;
    const char* gb0;
    const char* gb1;
    {
        const int row0 = tid >> 2;                     // B rows: op0 -> row0, op1 -> row0+128
        const int sc   = ((tid & 3) ^ (row0 >> 1)) & 3; // identical for row0+128 (128/2 % 4 == 0)
        int col = nt * 256 + row0;
        unsigned b = (unsigned)col / 626u;
        int tc = col - (int)b * 626;
        gb0 = xpb + ((size_t)b * XPAD_STRIDE + (size_t)tc * 512) * 2 + sc * 16;
        col = nt * 256 + 128 + row0;
        b = (unsigned)col / 626u;
        tc = col - (int)b * 626;
        gb1 = xpb + ((size_t)b * XPAD_STRIDE + (size_t)tc * 512) * 2 + sc * 16;
    }

    // ---- ds_read bases: row*64 + ((kq ^ (row>>1))&3)*16; (row>>1)&3 == (fr>>1)&3
    const unsigned swz = (unsigned)(((kq ^ (fr >> 1)) & 3) << 4);
    const unsigned offA_base = (unsigned)((wm * 64 + fr) * 64) + swz;
    const unsigned offB_base = (unsigned)((wn * 64 + fr) * 64) + swz;

    f32x4 acc[4][4];
    #pragma unroll
    for (int m = 0; m < 4; ++m)
        #pragma unroll
        for (int n = 0; n < 4; ++n)
            acc[m][n] = f32x4{0.f, 0.f, 0.f, 0.f};

    // ---- prologue: stage phases 0,1 (slots 0,1); phase 0's VM3 covers stage(0)
    STG(0, 0, 0);
    STG(0, 1, 1);

    // ---- main loop: phases 0..59 (6-phase period: slot 0,1,2,0,1,2; ks 0,1,0,1,0,1)
    #pragma unroll 1
    for (int i = 0; i < 10; ++i) {
        const int kb = 3 * i;
        PH3(0, STG(kb + 1, 0, 2);, VM3);
        PH3(1, STG(kb + 1, 1, 0);, VM3);
        PH3(2, STG(kb + 2, 0, 1);, VM3);
        PH3(0, STG(kb + 2, 1, 2);, VM3);
        PH3(1, STG(kb + 3, 0, 0);, VM3);
        PH3(2, STG(kb + 3, 1, 1);, VM3);
    }
    // ---- tail: phases 60..63
    PH3(0, STG(31, 0, 2);, VM3);
    PH3(1, STG(31, 1, 0);, VM3);
    PH3(2, , VM3);
    PH3(0, , VM0);

    // ---- epilogue: C/D layout col = lane&15, row = kq*4 + j
    const size_t imag_base = (size_t)B_BATCH * NFREQ * T_OUT;
    #pragma unroll
    for (int n = 0; n < 4; ++n) {
        const int col = nt * 256 + wn * 64 + n * 16 + fr;
        if (col < NCOLS) {
            const unsigned b = (unsigned)col / 626u;
            const int tc = col - (int)b * 626;
            const size_t colbase = (size_t)b * NFREQ * T_OUT + (size_t)tc;
            #pragma unroll
            for (int m = 0; m < 4; ++m) {
                #pragma unroll
                for (int j = 0; j < 4; ++j) {
                    const int grow = mt * 128 + wm * 64 + m * 16 + kq * 4 + j;
                    if (grow < M_ROWS) {
                        const size_t off = (grow < NFREQ)
                            ? colbase + (size_t)grow * T_OUT
                            : imag_base + colbase + (size_t)(grow - NFREQ) * T_OUT;
                        out[off] = acc[m][n][j];
                    }
                }
            }
        }
    }
}

// ---------------- no-workspace fallback (round-1 structure) ----------------
__device__ __forceinline__ unsigned lds_off_fb(int row, int kbyte) {
    return (unsigned)(row * 128 + (kbyte ^ ((row & 7) << 4)));
}

__global__ __launch_bounds__(256) void stft_gemm_fb(
    const float* __restrict__ x,
    const float* __restrict__ wre,
    const float* __restrict__ wim,
    float* __restrict__ out)
{
    __shared__ __align__(16) unsigned char ldsA[128 * 128];
    __shared__ __align__(16) unsigned char ldsB[128 * 128];

    const int tid  = threadIdx.x;
    const int lane = tid & 63;
    const int wid  = tid >> 6;
    const int wmf  = wid >> 1;
    const int wnf  = wid & 1;

    const int bid = blockIdx.x;
    const int b   = bid / (17 * 5);
    const int rem = bid % (17 * 5);
    const int mt  = rem / 5;
    const int nt  = rem % 5;

    const int row0 = mt * 128;
    const int col0 = nt * 128;
    const float* xb = x + (size_t)b * XLEN;

    const int c4 = (tid & 15) * 4;
    const int r0 = tid >> 4;

    f32x4 acc[4][4];
    #pragma unroll
    for (int m = 0; m < 4; ++m)
        #pragma unroll
        for (int n = 0; n < 4; ++n)
            acc[m][n] = f32x4{0.f, 0.f, 0.f, 0.f};

    const int fr = lane & 15;
    const int kq = lane >> 4;

    for (int k0 = 0; k0 < NFFT; k0 += 64) {
        bf16x4 sa[8], sb[8];
        #pragma unroll
        for (int rr = 0; rr < 8; ++rr) {
            const int row  = rr * 16 + r0;
            const int grow = row0 + row;
            float4 v = make_float4(0.f, 0.f, 0.f, 0.f);
            if (grow < M_ROWS) {
                const float* wsrc = (grow < NFREQ)
                    ? (wre + (size_t)grow * NFFT)
                    : (wim + (size_t)(grow - NFREQ) * NFFT);
                v = *reinterpret_cast<const float4*>(wsrc + k0 + c4);
            }
            sa[rr].x = (__bf16)v.x; sa[rr].y = (__bf16)v.y;
            sa[rr].z = (__bf16)v.z; sa[rr].w = (__bf16)v.w;
        }
        #pragma unroll
        for (int rr = 0; rr < 8; ++rr) {
            const int trow = rr * 16 + r0;
            const int t    = col0 + trow;
            float4 v = make_float4(0.f, 0.f, 0.f, 0.f);
            if (t < T_OUT) {
                const int pos = t * HOP + k0 + c4 - PADW;
                if (pos >= 0 && pos <= XLEN - 4) {
                    v = *reinterpret_cast<const float4*>(xb + pos);
                } else {
                    float tmp[4];
                    #pragma unroll
                    for (int e = 0; e < 4; ++e) {
                        int p = pos + e;
                        p = (p < 0) ? -p : p;
                        p = (p >= XLEN) ? (2 * XLEN - 2 - p) : p;
                        tmp[e] = xb[p];
                    }
                    v = make_float4(tmp[0], tmp[1], tmp[2], tmp[3]);
                }
            }
            sb[rr].x = (__bf16)v.x; sb[rr].y = (__bf16)v.y;
            sb[rr].z = (__bf16)v.z; sb[rr].w = (__bf16)v.w;
        }
        __syncthreads();
        #pragma unroll
        for (int rr = 0; rr < 8; ++rr) {
            const int row = rr * 16 + r0;
            *reinterpret_cast<bf16x4*>(ldsA + lds_off_fb(row, c4 * 2)) = sa[rr];
            *reinterpret_cast<bf16x4*>(ldsB + lds_off_fb(row, c4 * 2)) = sb[rr];
        }
        __syncthreads();
        #pragma unroll
        for (int kk = 0; kk < 2; ++kk) {
            const int kbyte = kk * 64 + kq * 16;
            bf16x8 af[4], bfv[4];
            #pragma unroll
            for (int m = 0; m < 4; ++m)
                af[m] = *reinterpret_cast<const bf16x8*>(
                    ldsA + lds_off_fb(wmf * 64 + m * 16 + fr, kbyte));
            #pragma unroll
            for (int n = 0; n < 4; ++n)
                bfv[n] = *reinterpret_cast<const bf16x8*>(
                    ldsB + lds_off_fb(wnf * 64 + n * 16 + fr, kbyte));
            #pragma unroll
            for (int m = 0; m < 4; ++m)
                #pragma unroll
                for (int n = 0; n < 4; ++n)
                    acc[m][n] = MFMA16(af[m], bfv[n], acc[m][n], 0, 0, 0);
        }
    }

    const size_t imag_base = (size_t)B_BATCH * NFREQ * T_OUT;
    #pragma unroll
    for (int m = 0; m < 4; ++m) {
        #pragma unroll
        for (int n = 0; n < 4; ++n) {
            #pragma unroll
            for (int j = 0; j < 4; ++j) {
                const int grow = row0 + wmf * 64 + m * 16 + kq * 4 + j;
                const int gcol = col0 + wnf * 64 + n * 16 + fr;
                if (grow < M_ROWS && gcol < T_OUT) {
                    size_t off;
                    if (grow < NFREQ)
                        off = ((size_t)b * NFREQ + grow) * T_OUT + gcol;
                    else
                        off = imag_base + ((size_t)b * NFREQ + (grow - NFREQ)) * T_OUT + gcol;
                    out[off] = acc[m][n][j];
                }
            }
        }
    }
}

extern "C" void kernel_launch(void* const* d_in, const int* in_sizes, int n_in,
                              void* d_out, int out_size, void* d_ws, size_t ws_size,
                              hipStream_t stream) {
    const float* x   = (const float*)d_in[0];
    const float* wre = (const float*)d_in[1];
    const float* wim = (const float*)d_in[2];
    float* out = (float*)d_out;

    if (ws_size < WS_NEEDED) {
        stft_gemm_fb<<<dim3(B_BATCH * 17 * 5), 256, 0, stream>>>(x, wre, wim, out);
        return;
    }

    __bf16* apack = (__bf16*)d_ws;
    __bf16* xpad  = (__bf16*)((char*)d_ws + APACK_BYTES);

    prep_w<<<dim3(557056 / 256), 256, 0, stream>>>(wre, wim, apack);
    prep_x<<<dim3(((B_BATCH + 1) * (XPAD_STRIDE / 8) + 255) / 256), 256, 0, stream>>>(x, xpad);
    stft_gemm4<<<dim3(MT2 * NT2), 512, 0, stream>>>(apack, xpad, out);
}